// Round 1
// baseline (79.843 us; speedup 1.0000x reference)
//
#include <hip/hip_runtime.h>
#include <math.h>

// 4-qubit, 2-layer circuit, batch-parallel statevector sim.
// One thread per batch element; 16 complex amps in registers.
// Wire w <-> bit (8>>w) of the flat index (q0 is MSB, matching (B,2,2,2,2) C-order).

__global__ void trig_kernel(const float* __restrict__ w, float* __restrict__ trig) {
    int i = threadIdx.x;
    if (i < 8) {
        float th = w[i] * 0.5f;
        trig[i]     = cosf(th);
        trig[i + 8] = sinf(th);
    }
}

// CNOT(ctrl->tgt): where ctrl bit set, swap tgt-bit pair. Pure register permutation.
#define CNOT(cb, tb)                                                  \
    {                                                                 \
        _Pragma("unroll") for (int i = 0; i < 16; i++)                \
            if ((i & (cb)) && !(i & (tb))) {                          \
                int j = i | (tb);                                     \
                float t;                                              \
                t = re[i]; re[i] = re[j]; re[j] = t;                  \
                t = im[i]; im[i] = im[j]; im[j] = t;                  \
            }                                                         \
    }

// RY(theta) on wire with bit mask `bit`: real rotation applied to re and im.
#define RY(bit, cc, ss)                                               \
    {                                                                 \
        _Pragma("unroll") for (int i = 0; i < 16; i++)                \
            if (!(i & (bit))) {                                       \
                int j = i | (bit);                                    \
                float r0 = re[i], r1 = re[j];                         \
                float i0 = im[i], i1 = im[j];                         \
                re[i] = (cc) * r0 - (ss) * r1;                        \
                re[j] = (ss) * r0 + (cc) * r1;                        \
                im[i] = (cc) * i0 - (ss) * i1;                        \
                im[j] = (ss) * i0 + (cc) * i1;                        \
            }                                                         \
    }

__global__ __launch_bounds__(256) void qc_kernel(const float* __restrict__ noise,
                                                 const float* __restrict__ trig,
                                                 float* __restrict__ out, int B) {
    int b = blockIdx.x * blockDim.x + threadIdx.x;
    if (b >= B) return;

    // Coalesced 16B load of this element's 4 RX angles.
    float4 nv = reinterpret_cast<const float4*>(noise)[b];
    float c0, s0, c1, s1, c2, s2, c3, s3;
    __sincosf(nv.x * 0.5f, &s0, &c0);
    __sincosf(nv.y * 0.5f, &s1, &c1);
    __sincosf(nv.z * 0.5f, &s2, &c2);
    __sincosf(nv.w * 0.5f, &s3, &c3);

    // Batch-uniform weight trig, precomputed in d_ws (compiler emits scalar loads).
    float wc[8], wsn[8];
#pragma unroll
    for (int i = 0; i < 8; i++) {
        wc[i]  = trig[i];
        wsn[i] = trig[i + 8];
    }

    // Post-RX product state: amp(i) = prod(c/s) * (-i)^popcount(i).
    float m01[4], m23[4];
    m01[0] = c0 * c1; m01[1] = c0 * s1; m01[2] = s0 * c1; m01[3] = s0 * s1;
    m23[0] = c2 * c3; m23[1] = c2 * s3; m23[2] = s2 * c3; m23[3] = s2 * s3;

    float re[16], im[16];
#pragma unroll
    for (int i = 0; i < 16; i++) {
        float m = m01[i >> 2] * m23[i & 3];
        int pc = __popc(i) & 3;
        re[i] = (pc == 0) ? m : (pc == 2) ? -m : 0.0f;
        im[i] = (pc == 1) ? -m : (pc == 3) ? m : 0.0f;
    }

    // 2 layers: CNOT ring (0->1,1->2,2->3,3->0) then RY on each wire.
#pragma unroll
    for (int layer = 0; layer < 2; layer++) {
        CNOT(8, 4);   // ctrl 0, tgt 1
        CNOT(4, 2);   // ctrl 1, tgt 2
        CNOT(2, 1);   // ctrl 2, tgt 3
        CNOT(1, 8);   // ctrl 3, tgt 0
        RY(8, wc[layer * 4 + 0], wsn[layer * 4 + 0]);
        RY(4, wc[layer * 4 + 1], wsn[layer * 4 + 1]);
        RY(2, wc[layer * 4 + 2], wsn[layer * 4 + 2]);
        RY(1, wc[layer * 4 + 3], wsn[layer * 4 + 3]);
    }

    // out[b][w] = sum of |amp|^2 over indices with wire-w bit clear.
    float p[16];
#pragma unroll
    for (int i = 0; i < 16; i++) p[i] = re[i] * re[i] + im[i] * im[i];

    float o0 = 0.f, o1 = 0.f, o2 = 0.f, o3 = 0.f;
#pragma unroll
    for (int i = 0; i < 16; i++) {
        if (!(i & 8)) o0 += p[i];
        if (!(i & 4)) o1 += p[i];
        if (!(i & 2)) o2 += p[i];
        if (!(i & 1)) o3 += p[i];
    }
    reinterpret_cast<float4*>(out)[b] = make_float4(o0, o1, o2, o3);
}

extern "C" void kernel_launch(void* const* d_in, const int* in_sizes, int n_in,
                              void* d_out, int out_size, void* d_ws, size_t ws_size,
                              hipStream_t stream) {
    const float* noise   = (const float*)d_in[0];   // (B, 4)
    const float* weights = (const float*)d_in[1];   // (2, 4)
    float* trig = (float*)d_ws;                      // 16 floats scratch
    float* out  = (float*)d_out;                     // (B, 4)
    int B = in_sizes[0] / 4;

    trig_kernel<<<1, 64, 0, stream>>>(weights, trig);
    qc_kernel<<<(B + 255) / 256, 256, 0, stream>>>(noise, trig, out, B);
}